// Round 5
// baseline (638.143 us; speedup 1.0000x reference)
//
#include <hip/hip_runtime.h>

// VectorQuantizer: z (32,256,32,32) f32, embedding (1024,256) f32.
// N=32768 rows (n = b*1024 + h*32 + w), D=256, K=1024.
// Out (f32, concat): z_q_st [8388608] (B,C,H,W), vq_loss [1], idx [32768].
// z_flat[n][c] = z[b*262144 + c*1024 + (n & 1023)]
//
// Fused kernel per 64-row block: f32 distance pass with (min1,min2,idx),
// then for rows with top-2 gap < TAU, re-derive the index by BIT-EXACT
// simulation of the numpy-f32 reference:
//   d32 = fl32(fl32(a32 - tb) + c32)
//   a32/c32: numpy pairwise-sum tree (two 128-blocks, 8 accumulators)
//   tb = 2 * b where b = BLAS-sgemm-style SEQUENTIAL f32 FMA chain over k
// ws: [0] double loss_sum, [64..4160) float enorm[1024] (np-pairwise values).

#define TAU 4.0e-4f

// numpy pairwise_sum for 256 f32 squares: two 128-blocks (8 accumulators,
// unrolled by 8), combined ((r0+r1)+(r2+r3))+((r4+r5)+(r6+r7)), then b0+b1.
// __fmul_rn/__fadd_rn forbid FMA contraction (bit-exact IEEE f32).
__device__ __forceinline__ float np_pairwise256_sq(const float* a) {
  float tot = 0.0f;
#pragma unroll
  for (int blk = 0; blk < 2; ++blk) {
    const float* p = a + blk * 128;
    float r[8];
#pragma unroll
    for (int j = 0; j < 8; ++j) r[j] = __fmul_rn(p[j], p[j]);
    for (int i = 8; i < 128; i += 8) {
#pragma unroll
      for (int j = 0; j < 8; ++j) r[j] = __fadd_rn(r[j], __fmul_rn(p[i + j], p[i + j]));
    }
    float res = __fadd_rn(__fadd_rn(__fadd_rn(r[0], r[1]), __fadd_rn(r[2], r[3])),
                          __fadd_rn(__fadd_rn(r[4], r[5]), __fadd_rn(r[6], r[7])));
    tot = (blk == 0) ? res : __fadd_rn(tot, res);
  }
  return tot;
}

__global__ void initK(double* loss_sum) { *loss_sum = 0.0; }

// enorm[k] = np-pairwise f32 sum of e_k^2 (bit-exact vs numpy reference).
__global__ __launch_bounds__(256) void enormK(const float* __restrict__ emb,
                                              float* __restrict__ enorm) {
  const int k = blockIdx.x * 256 + threadIdx.x;  // 4 blocks x 256
  enorm[k] = np_pairwise256_sq(emb + (size_t)k * 256);
}

__global__ __launch_bounds__(256) void fusedK(const float* __restrict__ z,
                                              const float* __restrict__ emb,
                                              const float* __restrict__ enorm,
                                              float* __restrict__ out,
                                              double* __restrict__ loss_sum) {
  __shared__ float smem[4096];             // 16 KiB staging (zl/el, later zrow)
  __shared__ int sidx[64];
  __shared__ unsigned long long sflag;     // rows needing np-f32 re-derivation
  __shared__ float swv[4];
  __shared__ int swi[4];
  __shared__ double sloss[4];

  float(*zl)[64] = (float(*)[64])smem;          // [32 d][64 m]
  float(*el)[64] = (float(*)[64])(smem + 2048); // [32 d][64 k]

  const int tid = threadIdx.x;
  const int tx = tid & 15;
  const int ty = tid >> 4;
  const int n0 = blockIdx.x * 64;
  const int b = n0 >> 10;
  const int hw0 = n0 & 1023;
  const float* zbase = z + (size_t)b * 262144 + hw0;

  if (tid == 0) sflag = 0ull;

  float m1[4], m2[4];
  int k1[4];
#pragma unroll
  for (int i = 0; i < 4; ++i) { m1[i] = 3.0e38f; m2[i] = 3.0e38f; k1[i] = 0; }

  // ---- phase 1: f32 distance pass, 16 k-tiles of 64, D chunked by 32 ----
  for (int kt = 0; kt < 16; ++kt) {
    float acc[4][4];
#pragma unroll
    for (int i = 0; i < 4; ++i)
#pragma unroll
      for (int j = 0; j < 4; ++j) acc[i][j] = 0.0f;

    for (int dc = 0; dc < 8; ++dc) {
      __syncthreads();  // protect LDS before overwrite
#pragma unroll
      for (int r = 0; r < 2; ++r) {  // z chunk: 32 c x 64 m
        int i = tid + r * 256;
        int c = i >> 4;
        int mq = (i & 15) << 2;
        float4 v = *(const float4*)(zbase + (size_t)(dc * 32 + c) * 1024 + mq);
        *(float4*)&zl[c][mq] = v;
      }
#pragma unroll
      for (int r = 0; r < 2; ++r) {  // e chunk: 64 k x 32 d -> [d][k]
        int i = tid + r * 256;
        int k = i >> 3;
        int dq = (i & 7) << 2;
        float4 v = *(const float4*)(emb + (size_t)(kt * 64 + k) * 256 + dc * 32 + dq);
        el[dq + 0][k] = v.x;
        el[dq + 1][k] = v.y;
        el[dq + 2][k] = v.z;
        el[dq + 3][k] = v.w;
      }
      __syncthreads();
#pragma unroll
      for (int d = 0; d < 32; ++d) {
        float4 a = *(const float4*)&zl[d][ty * 4];
        float4 bb = *(const float4*)&el[d][tx * 4];
        float av[4] = {a.x, a.y, a.z, a.w};
        float bv[4] = {bb.x, bb.y, bb.z, bb.w};
#pragma unroll
        for (int i = 0; i < 4; ++i)
#pragma unroll
          for (int j = 0; j < 4; ++j) acc[i][j] += av[i] * bv[j];
      }
    }
    float4 en = *(const float4*)(enorm + kt * 64 + tx * 4);
    float env[4] = {en.x, en.y, en.z, en.w};
#pragma unroll
    for (int i = 0; i < 4; ++i) {
#pragma unroll
      for (int j = 0; j < 4; ++j) {
        float v = env[j] - 2.0f * acc[i][j];
        int kg = kt * 64 + tx * 4 + j;
        if (v < m1[i]) {
          m2[i] = m1[i]; m1[i] = v; k1[i] = kg;
        } else if (v < m2[i]) {
          m2[i] = v;
        }
      }
    }
  }

  // ---- phase 2: cross-tx reduce via shfl (16-lane groups) ----
#pragma unroll
  for (int i = 0; i < 4; ++i) {
    float a1 = m1[i], a2 = m2[i];
    int ai = k1[i];
#pragma unroll
    for (int mask = 1; mask < 16; mask <<= 1) {
      float b1 = __shfl_xor(a1, mask);
      float b2 = __shfl_xor(a2, mask);
      int bi_ = __shfl_xor(ai, mask);
      if (b1 < a1 || (b1 == a1 && bi_ < ai)) {
        a2 = fminf(a1, b2); a1 = b1; ai = bi_;
      } else {
        a2 = fminf(a2, b1);
      }
    }
    if (tx == 0) {
      int r = ty * 4 + i;
      sidx[r] = ai;
      if (a2 - a1 < TAU) atomicOr(&sflag, 1ull << r);
    }
  }
  __syncthreads();

  // ---- phase 3: np-f32 bit-exact re-derivation for flagged rows ----
  unsigned long long flags = sflag;  // uniform across block
  while (flags) {
    int r = __ffsll(flags) - 1;
    flags &= flags - 1;
    float* zrow = smem;  // reuse staging LDS
    __syncthreads();
    zrow[tid] = z[(size_t)b * 262144 + (size_t)tid * 1024 + hw0 + r];
    __syncthreads();
    // a32 = np-pairwise sum of z_row^2 (computed redundantly by all threads)
    float a32 = np_pairwise256_sq(zrow);
    // b_k: BLAS-sgemm-style sequential f32 FMA chain over k (ascending d),
    // 4 independent chains per thread for ILP.
    const float* er0 = emb + (size_t)(tid * 4 + 0) * 256;
    const float* er1 = emb + (size_t)(tid * 4 + 1) * 256;
    const float* er2 = emb + (size_t)(tid * 4 + 2) * 256;
    const float* er3 = emb + (size_t)(tid * 4 + 3) * 256;
    float b0 = 0.0f, b1 = 0.0f, b2 = 0.0f, b3 = 0.0f;
    for (int d = 0; d < 256; ++d) {
      float zv = zrow[d];
      b0 = __fmaf_rn(zv, er0[d], b0);
      b1 = __fmaf_rn(zv, er1[d], b1);
      b2 = __fmaf_rn(zv, er2[d], b2);
      b3 = __fmaf_rn(zv, er3[d], b3);
    }
    float bch[4] = {b0, b1, b2, b3};
    float best = 3.0e38f;
    int bi = 1 << 30;
#pragma unroll
    for (int j = 0; j < 4; ++j) {
      const int k = tid * 4 + j;  // ascending per thread -> first-index wins
      // numpy: d = (a - (2z)@E^T) + c, all f32 elementwise; tb=2*b exact
      float tb = __fmul_rn(2.0f, bch[j]);
      float d32 = __fadd_rn(__fsub_rn(a32, tb), enorm[k]);
      if (d32 < best) { best = d32; bi = k; }  // strict < keeps first k
    }
    for (int mask = 1; mask < 64; mask <<= 1) {
      float ov = __shfl_xor(best, mask);
      int oi = __shfl_xor(bi, mask);
      if (ov < best || (ov == best && oi < bi)) { best = ov; bi = oi; }
    }
    if ((tid & 63) == 0) { swv[tid >> 6] = best; swi[tid >> 6] = bi; }
    __syncthreads();
    if (tid == 0) {
      float bv = swv[0];
      int bix = swi[0];
      for (int q = 1; q < 4; ++q)
        if (swv[q] < bv || (swv[q] == bv && swi[q] < bix)) { bv = swv[q]; bix = swi[q]; }
      sidx[r] = bix;
    }
    __syncthreads();
  }

  // ---- phase 4: outputs (f32) ----
  if (tid < 64) out[(size_t)8388609 + n0 + tid] = (float)sidx[tid];

  const int m = tid & 63;
  const int cq = tid >> 6;
  const float* erow = emb + (size_t)sidx[m] * 256;
  const size_t zb = (size_t)b * 262144 + hw0 + m;
  double acc = 0.0;
  for (int it = 0; it < 64; ++it) {
    int c = it * 4 + cq;
    float zv = zbase[(size_t)c * 1024 + m];
    float zq = erow[c];
    float d = zq - zv;
    out[zb + (size_t)c * 1024] = zv + d;  // z + (z_q - z), f32
    acc += (double)(d * d);
  }
  for (int mask = 1; mask < 64; mask <<= 1) acc += __shfl_xor(acc, mask);
  if ((tid & 63) == 0) sloss[tid >> 6] = acc;
  __syncthreads();
  if (tid == 0)
    atomicAdd(loss_sum, sloss[0] + sloss[1] + sloss[2] + sloss[3]);
}

__global__ void finalK(const double* loss_sum, float* out) {
  double s = *loss_sum;
  // vq_loss = (1 + beta) * mean((z_q - z)^2), beta = 0.25
  out[8388608] = (float)(1.25 * s / 8388608.0);
}

extern "C" void kernel_launch(void* const* d_in, const int* in_sizes, int n_in,
                              void* d_out, int out_size, void* d_ws, size_t ws_size,
                              hipStream_t stream) {
  const float* z = (const float*)d_in[0];
  const float* emb = (const float*)d_in[1];
  float* out = (float*)d_out;
  char* ws = (char*)d_ws;
  double* loss_sum = (double*)ws;
  float* enorm = (float*)(ws + 64);

  initK<<<1, 1, 0, stream>>>(loss_sum);
  enormK<<<4, 256, 0, stream>>>(emb, enorm);
  fusedK<<<512, 256, 0, stream>>>(z, emb, enorm, out, loss_sum);
  finalK<<<1, 1, 0, stream>>>(loss_sum, out);
}